// Round 4
// baseline (203.266 us; speedup 1.0000x reference)
//
#include <hip/hip_runtime.h>

// Fused quantized 3x3 conv, stride 1, pad 1 (MI355X / gfx950):
//   x: [32,64,112,112] fp32 -> uint4-range [0,15], quantized on the fly
//   w: [128,64,3,3]    fp32 -> int4-range  [-8,7]  (tiny k_quant_w pre-pass)
//   out: [32,128,112,112] fp32 (integer-exact)
//
// k_fused: one block per (n, 2-row strip). Stage 4 halo rows x 114 w x 64 c
// as int8 into LDS (channel dim padded to 80 B -> uniform bank coverage for
// both b128 writes and b128 MFMA reads), then implicit-GEMM with
// v_mfma_i32_16x16x64_i8. Weights straight from global (73.7 KB, L2-hot).
// Wave = 112 spatial x 32 cout = 7x2 tiles. 512 thr/block, 2 blocks/CU.

#define CIN  64
#define HH   112
#define WW   112
#define HW   (HH * WW)
#define COUT 128
#define KTOT 576              // 64*3*3

#define CP   80               // padded channel bytes (64 used), 16B-aligned
#define ROWB (114 * CP)       // 9120 B per halo row
#define NPOS (4 * 114)        // 456 staged (row,w) positions

#define NSTRIPS 56            // 112/2 rows per image
#define NBLK    (32 * NSTRIPS)  // 1792 = 8 * 224 (bijective XCD chunking)

typedef __attribute__((ext_vector_type(4))) int int32x4;

__global__ void k_quant_w(const float* __restrict__ w, char* __restrict__ wq) {
    int idx = blockIdx.x * 256 + threadIdx.x;       // 73728 total
    int o  = idx / KTOT;
    int r  = idx % KTOT;
    int kh = r / 192;
    int kw = (r / 64) % 3;
    int c  = r % 64;
    float v = w[((o * CIN + c) * 3 + kh) * 3 + kw];
    float q = fminf(fmaxf(rintf(v), -8.0f), 7.0f);   // RTNE == jnp.round
    wq[idx] = (char)(int)q;
}

__global__ __launch_bounds__(512, 4) void k_fused(const float* __restrict__ x,
                                                  const char* __restrict__ wq,
                                                  float* __restrict__ out) {
    __shared__ char xs[4 * ROWB];   // 36,480 B

    // Chunked XCD swizzle: consecutive strips land on the same XCD's L2,
    // so the 2 shared halo rows between neighbors are L2 hits.
    const int bid = blockIdx.x;
    const int swz = (bid & 7) * (NBLK / 8) + (bid >> 3);
    const int n  = swz / NSTRIPS;
    const int h0 = (swz % NSTRIPS) * 2;

    const float* xn = x + (size_t)n * (CIN * HW);
    const int tid = threadIdx.x;

    // ---- Stage + quantize 4 halo rows, all 64 channels ----
    if (tid < NPOS) {
        const int r  = tid / 114;
        const int w  = tid % 114;          // consecutive lanes -> consecutive w
        const int gh = h0 - 1 + r;
        const int gw = w - 1;
        const bool inb = ((unsigned)gh < HH) && ((unsigned)gw < WW);
        const float* px = xn + (ptrdiff_t)gh * WW + gw;
        unsigned int wb[16];
#pragma unroll
        for (int cw = 0; cw < 16; ++cw) {
            unsigned int word = 0;
#pragma unroll
            for (int j = 0; j < 4; ++j) {
                float v = inb ? px[(size_t)(cw * 4 + j) * HW] : 0.0f;
                float q = fminf(fmaxf(rintf(v), 0.0f), 15.0f);
                word |= ((unsigned int)(int)q) << (8 * j);
            }
            wb[cw] = word;
        }
        int32x4* d = (int32x4*)&xs[r * ROWB + w * CP];
#pragma unroll
        for (int i = 0; i < 4; ++i) {
            int32x4 v;
            v.x = (int)wb[i * 4 + 0];
            v.y = (int)wb[i * 4 + 1];
            v.z = (int)wb[i * 4 + 2];
            v.w = (int)wb[i * 4 + 3];
            d[i] = v;
        }
    }
    __syncthreads();

    // ---- Implicit GEMM ----
    const int wave = tid >> 6;        // 0..7
    const int lane = tid & 63;
    const int l15  = lane & 15;
    const int lk   = lane >> 4;       // 16-byte k-chunk within 64 channels
    const int r0   = wave >> 2;       // output row within strip (0..1)
    const int cobase = (wave & 3) * 32;

    // B (weights): lane l15 -> cout row, chunk lk; tO adds 16 rows, ks adds 64 B
    const char* wp0 = wq + (size_t)(cobase + l15) * KTOT + lk * 16;

    int32x4 acc[7][2];
#pragma unroll
    for (int i = 0; i < 7; ++i) {
        acc[i][0] = (int32x4)(0);
        acc[i][1] = (int32x4)(0);
    }

#pragma unroll
    for (int ks = 0; ks < 9; ++ks) {
        const int kh = ks / 3, kw = ks % 3;
        // A (activations): lane l15 -> spatial w within tile, chunk lk
        const char* arow = &xs[(r0 + kh) * ROWB + (l15 + kw) * CP + lk * 16];
        int32x4 af[7];
#pragma unroll
        for (int wt = 0; wt < 7; ++wt)
            af[wt] = *(const int32x4*)(arow + wt * 16 * CP);
#pragma unroll
        for (int tO = 0; tO < 2; ++tO) {
            const int32x4 bf = *(const int32x4*)(wp0 + (size_t)tO * 16 * KTOT + ks * 64);
#pragma unroll
            for (int wt = 0; wt < 7; ++wt)
                acc[wt][tO] = __builtin_amdgcn_mfma_i32_16x16x64_i8(af[wt], bf, acc[wt][tO], 0, 0, 0);
        }
    }

    // ---- Epilogue: D col(l15)=cout, row(lk*4+reg)=spatial w -> float4 stores ----
    const int gh = h0 + r0;
#pragma unroll
    for (int wt = 0; wt < 7; ++wt) {
#pragma unroll
        for (int tO = 0; tO < 2; ++tO) {
            const int co = cobase + tO * 16 + l15;
            float4 v;
            v.x = (float)acc[wt][tO][0];
            v.y = (float)acc[wt][tO][1];
            v.z = (float)acc[wt][tO][2];
            v.w = (float)acc[wt][tO][3];
            *(float4*)&out[(((size_t)n * COUT + co) * HH + gh) * WW + wt * 16 + lk * 4] = v;
        }
    }
}

extern "C" void kernel_launch(void* const* d_in, const int* in_sizes, int n_in,
                              void* d_out, int out_size, void* d_ws, size_t ws_size,
                              hipStream_t stream) {
    const float* x = (const float*)d_in[0];
    const float* w = (const float*)d_in[1];
    float* out = (float*)d_out;

    char* wq = (char*)d_ws;   // 73,728 B

    hipLaunchKernelGGL(k_quant_w, dim3((COUT * KTOT) / 256), dim3(256), 0, stream, w, wq);
    hipLaunchKernelGGL(k_fused, dim3(NBLK), dim3(512), 0, stream, x, wq, out);
}

// Round 5
// 105.851 us; speedup vs baseline: 1.9203x; 1.9203x over previous
//
#include <hip/hip_runtime.h>

// Quantized 3x3 conv, stride 1, pad 1 (MI355X / gfx950):
//   x: [32,64,112,112] fp32 -> uint4-range [0,15]
//   w: [128,64,3,3]    fp32 -> int4-range  [-8,7]
//   out: [32,128,112,112] fp32 (integer-exact)
//
// Two-kernel pipeline (round-2 skeleton, best measured 113.5 us):
//   k_prep: blocks 0..287 quantize+reorder weights -> wq[cout][kh][kw][cin];
//           blocks 288+  quantize+transpose x -> xq[n][hp][wp][c] int8,
//           padded 114x114 with zero border (2 rows per block).
//   k_conv: implicit GEMM with v_mfma_i32_16x16x64_i8.
//           Block = 256 thr / 4 waves, weights (one 64-cout half) in LDS.
//           Each block: 2 sequential 256-spatial chunks (stores of chunk 0
//           overlap loads of chunk 1). Explicit ks+1 activation prefetch.
//           XCD-chunked swizzle: consecutive ids = two cout-halves of the
//           same spatial chunk -> xq L2 reuse within an XCD.

#define CIN  64
#define HH   112
#define WW   112
#define HW   (HH * WW)
#define COUT 128
#define KTOT 576              // 64*3*3
#define HP   114
#define WP   114
#define LDSW 592              // 576 + 16 -> 2-way bank aliasing (free)

#define XQ_BYTES (32 * HP * WP * 64)     // 26,615,808
#define NWBLK 288                        // weight-quant blocks (288*256 = 73728)
#define NXBLK (32 * 57)                  // activation blocks (2 rows each)
#define NCONV 1568                       // 8 * 196, = (32*12544/256)*2 / 2

typedef __attribute__((ext_vector_type(4))) int int32x4;

__global__ __launch_bounds__(256) void k_prep(const float* __restrict__ x,
                                              const float* __restrict__ w,
                                              char* __restrict__ xq,
                                              char* __restrict__ wq) {
    const int bid = blockIdx.x, tid = threadIdx.x;
    if (bid < NWBLK) {
        // ---- weights: wq[o][kh][kw][c] ----
        int idx = bid * 256 + tid;
        int o  = idx / KTOT;
        int r  = idx % KTOT;
        int kh = r / 192;
        int kw = (r / 64) % 3;
        int c  = r % 64;
        float q = fminf(fmaxf(rintf(w[((o * CIN + c) * 3 + kh) * 3 + kw]), -8.0f), 7.0f);
        wq[idx] = (char)(int)q;
        return;
    }
    // ---- activations: xq[n][hp][wp][c], zero border ----
    const int rid = bid - NWBLK;          // 0..1823
    const int n  = rid / 57;
    const int hp = (rid % 57) * 2 + (tid >> 7);
    const int wp = tid & 127;
    if (wp >= WP) return;
    char* dst = xq + (((size_t)n * HP + hp) * WP + wp) * 64;
    int32x4* d4 = (int32x4*)dst;
    if (hp == 0 || hp == HP - 1 || wp == 0 || wp == WP - 1) {
#pragma unroll
        for (int i = 0; i < 4; ++i) d4[i] = (int32x4)(0);
        return;
    }
    const int h = hp - 1, ww = wp - 1;
    const float* px = x + (((size_t)n * CIN) * HH + h) * WW + ww;
    unsigned int buf[16];
#pragma unroll
    for (int cw = 0; cw < 16; ++cw) {
        unsigned int word = 0;
#pragma unroll
        for (int j = 0; j < 4; ++j) {
            float v = px[(size_t)(cw * 4 + j) * HW];
            float q = fminf(fmaxf(rintf(v), 0.0f), 15.0f);
            word |= ((unsigned int)(int)q) << (8 * j);
        }
        buf[cw] = word;
    }
#pragma unroll
    for (int i = 0; i < 4; ++i) {
        int32x4 v;
        v.x = (int)buf[i * 4 + 0];
        v.y = (int)buf[i * 4 + 1];
        v.z = (int)buf[i * 4 + 2];
        v.w = (int)buf[i * 4 + 3];
        d4[i] = v;
    }
}

__global__ __launch_bounds__(256) void k_conv(const char* __restrict__ xq,
                                              const char* __restrict__ wq,
                                              float* __restrict__ out) {
    __shared__ char wlds[64 * LDSW];   // 37,888 B

    const int tid = threadIdx.x;
    // XCD chunking (1568 = 8*196, bijective). Within a chunk, ids are
    // consecutive: nid 2k/2k+1 = the two cout-halves of spatial chunk-pair k.
    const int nid  = (blockIdx.x & 7) * (NCONV / 8) + (blockIdx.x >> 3);
    const int half = nid & 1;
    const int pb   = nid >> 1;          // 0..783, chunk pair {2pb, 2pb+1}

    // ---- stage this half's weights (64 rows x 36 x 16B) ----
    const char* wsrc = wq + (size_t)half * (64 * KTOT);
    for (int i = tid; i < 64 * (KTOT / 16); i += 256) {
        int row = i / 36, ch = i % 36;
        *(int32x4*)(&wlds[row * LDSW + ch * 16]) =
            *(const int32x4*)(wsrc + row * KTOT + ch * 16);
    }
    __syncthreads();

    const int wave = tid >> 6;
    const int lane = tid & 63;
    const int l15  = lane & 15;
    const int lk   = lane >> 4;
    const int cobase = 0;                // within-half; half offset applied at store

#pragma unroll
    for (int it = 0; it < 2; ++it) {
        const int chunk = pb * 2 + it;           // 0..1567, 256 sp each
        const int n  = chunk / 49;               // 12544 = 49*256
        const int s0 = (chunk % 49) * 256 + wave * 64;
        const char* xbase = xq + (size_t)n * (HP * WP * 64);

        int saddr[4];
#pragma unroll
        for (int tS = 0; tS < 4; ++tS) {
            int sl = s0 + tS * 16 + l15;
            int hh = sl / WW;
            int ww = sl - hh * WW;
            saddr[tS] = (hh * WP + ww) * 64 + lk * 16;
        }

        int32x4 acc[4][4];   // [tS][tO]
#pragma unroll
        for (int i = 0; i < 4; ++i)
#pragma unroll
            for (int j = 0; j < 4; ++j) acc[i][j] = (int32x4)(0);

        // koff for ks: kh=ks/3, kw=ks%3 -> (kh*WP + kw)*64
        int32x4 af[4], afn[4];
#pragma unroll
        for (int tS = 0; tS < 4; ++tS)
            af[tS] = *(const int32x4*)(xbase + saddr[tS]);   // ks=0: koff=0

#pragma unroll
        for (int ks = 0; ks < 9; ++ks) {
            if (ks < 8) {
                const int ksn = ks + 1;
                const int koffn = ((ksn / 3) * WP + (ksn % 3)) * 64;
#pragma unroll
                for (int tS = 0; tS < 4; ++tS)
                    afn[tS] = *(const int32x4*)(xbase + saddr[tS] + koffn);
            }
#pragma unroll
            for (int tO = 0; tO < 4; ++tO) {
                const int32x4 bf = *(const int32x4*)(
                    &wlds[(cobase + tO * 16 + l15) * LDSW + lk * 16 + ks * 64]);
#pragma unroll
                for (int tS = 0; tS < 4; ++tS)
                    acc[tS][tO] = __builtin_amdgcn_mfma_i32_16x16x64_i8(af[tS], bf, acc[tS][tO], 0, 0, 0);
            }
#pragma unroll
            for (int tS = 0; tS < 4; ++tS) af[tS] = afn[tS];
        }

        // ---- epilogue: D col(l15)=cout, row(lk*4+reg)=spatial ----
        float* obase = out + (size_t)n * (COUT * HW) + (size_t)half * 64 * HW;
#pragma unroll
        for (int tS = 0; tS < 4; ++tS) {
#pragma unroll
            for (int tO = 0; tO < 4; ++tO) {
                const int co = tO * 16 + l15;
                const int sl = s0 + tS * 16 + lk * 4;
                float4 v;
                v.x = (float)acc[tS][tO][0];
                v.y = (float)acc[tS][tO][1];
                v.z = (float)acc[tS][tO][2];
                v.w = (float)acc[tS][tO][3];
                *(float4*)(&obase[(size_t)co * HW + sl]) = v;
            }
        }
    }
}

extern "C" void kernel_launch(void* const* d_in, const int* in_sizes, int n_in,
                              void* d_out, int out_size, void* d_ws, size_t ws_size,
                              hipStream_t stream) {
    const float* x = (const float*)d_in[0];
    const float* w = (const float*)d_in[1];
    float* out = (float*)d_out;

    char* xq = (char*)d_ws;
    char* wq = xq + XQ_BYTES;

    hipLaunchKernelGGL(k_prep, dim3(NWBLK + NXBLK), dim3(256), 0, stream, x, w, xq, wq);
    hipLaunchKernelGGL(k_conv, dim3(NCONV), dim3(256), 0, stream, xq, wq, out);
}